// Round 1
// baseline (212.535 us; speedup 1.0000x reference)
//
#include <hip/hip_runtime.h>

// Valid 3x3 cross-correlation + scalar bias.
// x: [8192][8192] f32 -> out: [8190][8190] f32.
// Memory-bound: ~537 MB traffic, roofline ~85 us @ 6.3 TB/s.

static constexpr int H  = 8192;
static constexpr int W  = 8192;
static constexpr int OH = H - 2;   // 8190
static constexpr int OW = W - 2;   // 8190

// Each thread: 1 output row x 4 output cols (float4 store).
// blockDim = (64, 4); gridDim = (ceil(OW/4/64)=32, ceil(OH/4)=2048).
__global__ __launch_bounds__(256) void conv3x3_kernel(
    const float* __restrict__ x,
    const float* __restrict__ w,
    const float* __restrict__ bias,
    float* __restrict__ out)
{
    const int c = (blockIdx.x * 64 + threadIdx.x) * 4;  // output col base
    const int r = blockIdx.y * 4 + threadIdx.y;         // output row
    if (r >= OH || c >= OW) return;

    // 3x3 weights in registers (scalar loads; broadcast, L2-resident).
    float wk[3][3];
    #pragma unroll
    for (int i = 0; i < 3; ++i)
        #pragma unroll
        for (int j = 0; j < 3; ++j)
            wk[i][j] = w[i * 3 + j];
    const float b = bias[0];

    float acc0 = b, acc1 = b, acc2 = b, acc3 = b;

    if (c + 6 <= W) {
        // Fast path: rows r..r+2, cols c..c+5 all in-bounds
        // (r+2 <= 8191 always since r <= 8189).
        #pragma unroll
        for (int kr = 0; kr < 3; ++kr) {
            const float* row = x + (size_t)(r + kr) * W + c;
            const float4 v = *reinterpret_cast<const float4*>(row);
            const float v4 = row[4];
            const float v5 = row[5];
            const float k0 = wk[kr][0], k1 = wk[kr][1], k2 = wk[kr][2];
            acc0 = fmaf(k0, v.x, fmaf(k1, v.y, fmaf(k2, v.z, acc0)));
            acc1 = fmaf(k0, v.y, fmaf(k1, v.z, fmaf(k2, v.w, acc1)));
            acc2 = fmaf(k0, v.z, fmaf(k1, v.w, fmaf(k2, v4, acc2)));
            acc3 = fmaf(k0, v.w, fmaf(k1, v4, fmaf(k2, v5, acc3)));
        }
        if (c + 4 <= OW) {
            float4 o; o.x = acc0; o.y = acc1; o.z = acc2; o.w = acc3;
            *reinterpret_cast<float4*>(out + (size_t)r * OW + c) = o;
        } else {
            // c == 8188: only 2 valid outputs
            float* orow = out + (size_t)r * OW + c;
            orow[0] = acc0;
            if (c + 1 < OW) orow[1] = acc1;
        }
    } else {
        // Tail col group (c == 8188): cols c..c+3 valid in x; c+4, c+5 OOB.
        // The OOB values only feed acc2/acc3, whose outputs are OOB too.
        #pragma unroll
        for (int kr = 0; kr < 3; ++kr) {
            const float* row = x + (size_t)(r + kr) * W + c;
            const float4 v = *reinterpret_cast<const float4*>(row);
            const float k0 = wk[kr][0], k1 = wk[kr][1], k2 = wk[kr][2];
            acc0 = fmaf(k0, v.x, fmaf(k1, v.y, fmaf(k2, v.z, acc0)));
            acc1 = fmaf(k0, v.y, fmaf(k1, v.z, fmaf(k2, v.w, acc1)));
        }
        float* orow = out + (size_t)r * OW + c;
        if (c     < OW) orow[0] = acc0;
        if (c + 1 < OW) orow[1] = acc1;
    }
}

extern "C" void kernel_launch(void* const* d_in, const int* in_sizes, int n_in,
                              void* d_out, int out_size, void* d_ws, size_t ws_size,
                              hipStream_t stream) {
    const float* x    = (const float*)d_in[0];
    const float* w    = (const float*)d_in[1];
    const float* bias = (const float*)d_in[2];
    float* out        = (float*)d_out;

    dim3 block(64, 4, 1);
    dim3 grid((OW + 4 * 64 - 1) / (4 * 64),   // 32
              (OH + 4 - 1) / 4,               // 2048
              1);
    conv3x3_kernel<<<grid, block, 0, stream>>>(x, w, bias, out);
}

// Round 2
// 93.337 us; speedup vs baseline: 2.2771x; 2.2771x over previous
//
#include <hip/hip_runtime.h>

// Valid 3x3 cross-correlation + scalar bias.
// x: [8192][8192] f32 -> out: [8190][8190] f32.
// Memory-bound: ~425-537 MB HBM traffic, roofline ~67-85 us @ 6.3 TB/s.
//
// Round 1 was latency-bound (VGPR=16, 1.9 TB/s, VALUBusy 9%). This version:
// each thread computes a 4-row x 8-col output tile; all 6 input rows (10 cols)
// loaded up-front = 24 independent loads, 240 B in flight per thread.
// Non-temporal stores keep the write-once output from thrashing L2.

static constexpr int H  = 8192;
static constexpr int W  = 8192;
static constexpr int OH = H - 2;   // 8190
static constexpr int OW = W - 2;   // 8190

typedef float f32x4 __attribute__((ext_vector_type(4)));

// blockDim = (64, 4): covers 512 cols x 16 rows per block.
// gridDim  = (ceil(8190/512)=16, ceil(8190/16)=512).
__global__ __launch_bounds__(256) void conv3x3_kernel(
    const float* __restrict__ x,
    const float* __restrict__ w,
    const float* __restrict__ bias,
    float* __restrict__ out)
{
    const int c = (blockIdx.x * 64 + (int)threadIdx.x) * 8;  // output col base
    const int r = (blockIdx.y * 4 + (int)threadIdx.y) * 4;   // output row base
    if (r >= OH || c >= OW) return;

    float wk[3][3];
    #pragma unroll
    for (int i = 0; i < 3; ++i)
        #pragma unroll
        for (int j = 0; j < 3; ++j)
            wk[i][j] = w[i * 3 + j];
    const float b = bias[0];

    // Only the last col-group (c == 8184) lacks cols c+8, c+9; its two extra
    // inputs only feed outputs j=6,7 which are OOB there anyway.
    const bool colFast = (c + 10 <= W);

    // Load 6 input rows x 10 cols up-front. Rows clamped for the last row
    // block (outputs from clamped rows are never stored).
    float in[6][10];
    #pragma unroll
    for (int t = 0; t < 6; ++t) {
        int rr = r + t; rr = (rr < H) ? rr : (H - 1);
        const float* row = x + (size_t)rr * W + c;
        const f32x4 va = *reinterpret_cast<const f32x4*>(row);
        const f32x4 vb = *reinterpret_cast<const f32x4*>(row + 4);
        in[t][0] = va.x; in[t][1] = va.y; in[t][2] = va.z; in[t][3] = va.w;
        in[t][4] = vb.x; in[t][5] = vb.y; in[t][6] = vb.z; in[t][7] = vb.w;
        if (colFast) { in[t][8] = row[8]; in[t][9] = row[9]; }
        else         { in[t][8] = 0.0f;   in[t][9] = 0.0f;   }
    }

    float acc[4][8];
    #pragma unroll
    for (int i = 0; i < 4; ++i)
        #pragma unroll
        for (int j = 0; j < 8; ++j)
            acc[i][j] = b;

    // All indices compile-time after unrolling (rule: no runtime-indexed
    // register arrays).
    #pragma unroll
    for (int i = 0; i < 4; ++i) {
        #pragma unroll
        for (int kr = 0; kr < 3; ++kr) {
            const int t = i + kr;
            const float k0 = wk[kr][0], k1 = wk[kr][1], k2 = wk[kr][2];
            #pragma unroll
            for (int j = 0; j < 8; ++j)
                acc[i][j] = fmaf(k0, in[t][j],
                            fmaf(k1, in[t][j + 1],
                            fmaf(k2, in[t][j + 2], acc[i][j])));
        }
    }

    #pragma unroll
    for (int i = 0; i < 4; ++i) {
        if (r + i < OH) {
            float* orow = out + (size_t)(r + i) * OW + c;
            if (c + 8 <= OW) {
                f32x4 o0 = { acc[i][0], acc[i][1], acc[i][2], acc[i][3] };
                f32x4 o1 = { acc[i][4], acc[i][5], acc[i][6], acc[i][7] };
                __builtin_nontemporal_store(o0, reinterpret_cast<f32x4*>(orow));
                __builtin_nontemporal_store(o1, reinterpret_cast<f32x4*>(orow + 4));
            } else {
                // c == 8184: outputs j=0..5 valid (c+5 == 8189 == OW-1).
                f32x4 o0 = { acc[i][0], acc[i][1], acc[i][2], acc[i][3] };
                __builtin_nontemporal_store(o0, reinterpret_cast<f32x4*>(orow));
                orow[4] = acc[i][4];
                orow[5] = acc[i][5];
            }
        }
    }
}

extern "C" void kernel_launch(void* const* d_in, const int* in_sizes, int n_in,
                              void* d_out, int out_size, void* d_ws, size_t ws_size,
                              hipStream_t stream) {
    const float* x    = (const float*)d_in[0];
    const float* w    = (const float*)d_in[1];
    const float* bias = (const float*)d_in[2];
    float* out        = (float*)d_out;

    dim3 block(64, 4, 1);
    dim3 grid((OW + 512 - 1) / 512,    // 16
              (OH + 16 - 1) / 16,      // 512
              1);
    conv3x3_kernel<<<grid, block, 0, stream>>>(x, w, bias, out);
}